// Round 14
// baseline (361.074 us; speedup 1.0000x reference)
//
#include <hip/hip_runtime.h>
#include <stdint.h>

// Fused causal single-head attention: x[512,256,384] f32, W*[384,64] f32 -> out[512,256,64] f32.
// One block per batch: 1024 threads = 16 waves; wave w owns q-rows [16w,16w+16).
// Fragment math identical to the round-12 HW-validated kernel; re-partitioned for occupancy:
//  - x loaded DIRECTLY from global per wave (never shared across waves -> no xs LDS, no staging barriers)
//  - W^T staged ONCE per matrix (48KB full tile), not 12x per matrix -> 9 barriers total (was 26)
//  - __launch_bounds__(1024,4): 16 waves/CU target (round-12 measured 22% occ = 1x8 waves, latency-bound)

namespace {
constexpr int kT = 256;
constexpr int kE = 384;
constexpr int kH = 64;
}

typedef __attribute__((ext_vector_type(8))) short short8;
typedef __attribute__((ext_vector_type(4))) short short4v;
typedef __attribute__((ext_vector_type(4))) float floatx4;

__device__ __forceinline__ uint16_t f2bf(float f) {
    union { float f; uint32_t u; } c; c.f = f;
    uint32_t u = c.u + 0x7FFFu + ((c.u >> 16) & 1u);   // RNE
    return (uint16_t)(u >> 16);
}
__device__ __forceinline__ uint32_t pk2(float lo, float hi) {
    return (uint32_t)f2bf(lo) | ((uint32_t)f2bf(hi) << 16);
}
__device__ __forceinline__ floatx4 mfma32(short8 a, short8 b, floatx4 c) {
    return __builtin_amdgcn_mfma_f32_16x16x32_bf16(a, b, c, 0, 0, 0);
}
__device__ __forceinline__ floatx4 mfma16(short4v a, short4v b, floatx4 c) {
    return __builtin_amdgcn_mfma_f32_16x16x16bf16_1k(a, b, c, 0, 0, 0);
}

// LDS phase union (64 KiB):
//  proj:  W^T [64 h][384 e] bf16 swz=(h&7)<<4            @0      (48 KB)
//  Qdump: per-wave [16 q][64 h] bf16 swz=(l15&7)<<4      @w*2048 (32 KB)
//  attn:  Ks [256 s][64 h] bf16 swz=(s&7)<<4             @0      (32 KB)
//         VsT [64 h][256 s] bf16 swz=(h&7)<<4            @32768  (32 KB)
#define WS_OFF 0
#define QS_OFF 0
#define KS_OFF 0
#define VS_OFF 32768

__global__ __launch_bounds__(1024, 4) void head_mfma16_kernel(
    const float* __restrict__ x,
    const float* __restrict__ Wk,
    const float* __restrict__ Wq,
    const float* __restrict__ Wv,
    float* __restrict__ out)
{
    __shared__ uint8_t lds[65536];

    const int b   = blockIdx.x;
    const int tid = threadIdx.x;
    const int w   = tid >> 6;          // wave 0..15
    const int l15 = tid & 15;
    const int g   = (tid & 63) >> 4;   // 16-lane group 0..3

    const float* xrow = x + ((size_t)(b * kT + 16 * w + l15)) * kE;

    floatx4 kacc[4] = {};   // K[t][h]: col h=l15(+16nt), row t=16w+4g+r
    floatx4 vacc[4] = {};
    floatx4 qacc[4] = {};   // Q^T[h][t]: col t=l15, row h=16mt+4g+r

    // ---- stage one W^T matrix: [64][384] bf16, rows 768B, swz byte ^= (h&7)<<4 ----
    auto stageW = [&](const float* __restrict__ W) {
        for (int i = tid; i < 3072; i += 1024) {        // 64 h x 48 16B-chunks
            const int h = i & 63, c16 = i >> 6;
            const float* s = W + (size_t)(c16 * 8) * kH + h;
            uint4 v;
            v.x = pk2(s[0],      s[kH]);
            v.y = pk2(s[2 * kH], s[3 * kH]);
            v.z = pk2(s[4 * kH], s[5 * kH]);
            v.w = pk2(s[6 * kH], s[7 * kH]);
            *reinterpret_cast<uint4*>(lds + WS_OFF + h * 768 + ((c16 * 16) ^ ((h & 7) << 4))) = v;
        }
    };
    auto loadX = [&](int ks) -> short8 {
        const float4 a  = *reinterpret_cast<const float4*>(xrow + ks * 32 + g * 8);
        const float4 b2 = *reinterpret_cast<const float4*>(xrow + ks * 32 + g * 8 + 4);
        uint4 u;
        u.x = pk2(a.x, a.y);  u.y = pk2(a.z, a.w);
        u.z = pk2(b2.x, b2.y); u.w = pk2(b2.z, b2.w);
        return __builtin_bit_cast(short8, u);
    };
    auto loadW = [&](int nt, int ks) -> short8 {
        const int h = 16 * nt + l15;
        return *reinterpret_cast<const short8*>(
            lds + WS_OFF + h * 768 + ((64 * ks + 16 * g) ^ ((h & 7) << 4)));
    };

    // ---------------- projections: 3 barrier-free streams ----------------
    stageW(Wk); __syncthreads();
    for (int ks = 0; ks < kE / 32; ++ks) {
        const short8 xf = loadX(ks);
#pragma unroll
        for (int nt = 0; nt < 4; ++nt) kacc[nt] = mfma32(xf, loadW(nt, ks), kacc[nt]);
    }
    __syncthreads();
    stageW(Wq); __syncthreads();
    for (int ks = 0; ks < kE / 32; ++ks) {
        const short8 xf = loadX(ks);
#pragma unroll
        for (int mt = 0; mt < 4; ++mt) qacc[mt] = mfma32(loadW(mt, ks), xf, qacc[mt]);
    }
    __syncthreads();
    stageW(Wv); __syncthreads();
    for (int ks = 0; ks < kE / 32; ++ks) {
        const short8 xf = loadX(ks);
#pragma unroll
        for (int nt = 0; nt < 4; ++nt) vacc[nt] = mfma32(xf, loadW(nt, ks), vacc[nt]);
    }
    __syncthreads();

    // ---------------- Q round-trip (wave-local 2KB region) ----------------
#pragma unroll
    for (int mt = 0; mt < 4; ++mt) {
        uint2 v; v.x = pk2(qacc[mt][0], qacc[mt][1]); v.y = pk2(qacc[mt][2], qacc[mt][3]);
        *reinterpret_cast<uint2*>(
            lds + QS_OFF + w * 2048 + l15 * 128 + (((16 * mt + 4 * g) * 2) ^ ((l15 & 7) << 4))) = v;
    }
    short4v qf[4];   // B-frag: col q=l15, k=h=16kst+4g+j
#pragma unroll
    for (int kst = 0; kst < 4; ++kst)
        qf[kst] = *reinterpret_cast<const short4v*>(
            lds + QS_OFF + w * 2048 + l15 * 128 + (((16 * kst + 4 * g) * 2) ^ ((l15 & 7) << 4)));
    __syncthreads();   // protect WAR: K dump reuses the Q region

    // ---------------- K/V dump ----------------
#pragma unroll
    for (int nt = 0; nt < 4; ++nt)
#pragma unroll
        for (int r = 0; r < 4; ++r) {
            const int s = 16 * w + 4 * g + r;
            const int h = 16 * nt + l15;
            *reinterpret_cast<uint16_t*>(
                lds + KS_OFF + s * 128 + ((h * 2) ^ ((s & 7) << 4))) = f2bf(kacc[nt][r]);
        }
#pragma unroll
    for (int nt = 0; nt < 4; ++nt) {
        const int h = 16 * nt + l15;
        uint2 v; v.x = pk2(vacc[nt][0], vacc[nt][1]); v.y = pk2(vacc[nt][2], vacc[nt][3]);
        *reinterpret_cast<uint2*>(
            lds + VS_OFF + h * 512 + (((16 * w + 4 * g) * 2) ^ ((h & 7) << 4))) = v;
    }
    __syncthreads();

    // ---------------- causal attention: wave w = q-tile w, c-blocks of 64 ----------------
    floatx4 oacc[4] = {};   // O[q][h]: col h=l15(+16nth), row q=16w+4g+r
    floatx4 lacc    = {};
    const short4v ones = { (short)0x3F80, (short)0x3F80, (short)0x3F80, (short)0x3F80 };
    const int cdiag = w >> 2;

    for (int c = 0; c <= cdiag; ++c) {
        floatx4 sacc[4] = {};   // S^T[s][q]: col q=l15, row s=64c+16mt+4g+r
#pragma unroll
        for (int kst = 0; kst < 4; ++kst) {
            short4v kf[4];
#pragma unroll
            for (int mt = 0; mt < 4; ++mt) {
                const int s = 64 * c + 16 * mt + l15;
                kf[mt] = *reinterpret_cast<const short4v*>(
                    lds + KS_OFF + s * 128 + (((16 * kst + 4 * g) * 2) ^ ((s & 7) << 4)));
            }
#pragma unroll
            for (int mt = 0; mt < 4; ++mt)
                sacc[mt] = mfma16(kf[mt], qf[kst], sacc[mt]);
        }
        const bool diag = (c == cdiag);
        short4v pf[4];
#pragma unroll
        for (int st = 0; st < 4; ++st) {
            float pr[4];
#pragma unroll
            for (int r = 0; r < 4; ++r) {
                const int s = 64 * c + 16 * st + 4 * g + r;
                const float e = __expf(sacc[st][r] * 0.125f);   // scale 1/sqrt(64)
                pr[r] = (diag && (s > 16 * w + l15)) ? 0.0f : e;
            }
            pf[st] = short4v{ (short)f2bf(pr[0]), (short)f2bf(pr[1]),
                              (short)f2bf(pr[2]), (short)f2bf(pr[3]) };
            lacc = mfma16(pf[st], ones, lacc);
        }
#pragma unroll
        for (int kst = 0; kst < 4; ++kst)
#pragma unroll
            for (int nth = 0; nth < 4; ++nth) {
                const int h = 16 * nth + l15;
                const short4v vf = *reinterpret_cast<const short4v*>(
                    lds + VS_OFF + h * 512 + (((64 * c + 16 * kst + 4 * g) * 2) ^ ((h & 7) << 4)));
                oacc[nth] = mfma16(pf[kst], vf, oacc[nth]);
            }
    }

    // ---------------- epilogue ----------------
#pragma unroll
    for (int r = 0; r < 4; ++r) {
        const float inv = 1.0f / lacc[r];
        const int q = 16 * w + 4 * g + r;
#pragma unroll
        for (int nth = 0; nth < 4; ++nth)
            out[((size_t)(b * kT + q)) * kH + 16 * nth + l15] = oacc[nth][r] * inv;
    }
}

extern "C" void kernel_launch(void* const* d_in, const int* in_sizes, int n_in,
                              void* d_out, int out_size, void* d_ws, size_t ws_size,
                              hipStream_t stream) {
    const float* x  = (const float*)d_in[0];
    const float* Wk = (const float*)d_in[1];
    const float* Wq = (const float*)d_in[2];
    const float* Wv = (const float*)d_in[3];
    float* out = (float*)d_out;

    head_mfma16_kernel<<<dim3(512), dim3(1024), 0, stream>>>(x, Wk, Wq, Wv, out);
}